// Round 4
// baseline (464.600 us; speedup 1.0000x reference)
//
#include <hip/hip_runtime.h>
#include <math.h>
#include <float.h>

#define IN_DIM 256
#define OUT_DIM 512
#define MEM_LEN 131072
#define K_TOP 16

#define GEMV_BLOCKS 32
#define K_PER_BLOCK (IN_DIM / GEMV_BLOCKS)     // 8
#define DIST_BLOCKS 2048
#define ROWS_PER_BLOCK (MEM_LEN / DIST_BLOCKS) // 64
#define CAND_N (DIST_BLOCKS * K_TOP)           // 32768

// ---------------------------------------------------------------------------
// Kernel 1: split-K GEMV partials, no atomics, no init dependency.
// Block g: partial[g][t] = sum_{k in slice g} xn[k]*W[k][t]  (+ b[t] on g==0).
__global__ void gemv_partial_kernel(const float* __restrict__ data,
                                    const float* __restrict__ mean,
                                    const float* __restrict__ stdv,
                                    const float* __restrict__ W,
                                    const float* __restrict__ b,
                                    float* __restrict__ partial) {
    __shared__ float xn_s[K_PER_BLOCK];
    const int t = threadIdx.x;        // column 0..511
    const int g = blockIdx.x;         // K-slice
    if (t < K_PER_BLOCK) {
        int i = g * K_PER_BLOCK + t;
        float s = stdv[i];
        xn_s[t] = (s == 0.0f) ? 0.0f : (data[i] - mean[i]) / s;
    }
    __syncthreads();
    float acc = (g == 0) ? b[t] : 0.0f;
#pragma unroll
    for (int j = 0; j < K_PER_BLOCK; ++j)
        acc = fmaf(xn_s[j], W[(g * K_PER_BLOCK + j) * OUT_DIM + t], acc);
    partial[g * OUT_DIM + t] = acc;
}

// ---------------------------------------------------------------------------
// Kernel 2: fused enc-reduce + dist stream + per-block top-16.
// 2048 blocks x 256 threads (4 waves, 16 consecutive rows per wave).
// Wave 0 reduces the 32 GEMV partials -> enc (tanh) into LDS; all waves load
// their lane's float4 fragments; stream 64 rows; wave 0 extracts the block's
// 16 smallest dists in-register and writes them to cand.
__global__ __launch_bounds__(256)
void dist_topk_kernel(const float* __restrict__ partial,
                      const float* __restrict__ memory,
                      float* __restrict__ cand) {
    __shared__ float es[OUT_DIM];
    __shared__ float bd[ROWS_PER_BLOCK];
    const int t = threadIdx.x;
    const int lane = t & 63;
    const int w = t >> 6;

    if (t < 64) {
        float4 s0 = make_float4(0.f, 0.f, 0.f, 0.f);
        float4 s1 = make_float4(0.f, 0.f, 0.f, 0.f);
#pragma unroll 8
        for (int g = 0; g < GEMV_BLOCKS; ++g) {
            const float4 p0 = *(const float4*)(partial + g * OUT_DIM + lane * 4);
            const float4 p1 = *(const float4*)(partial + g * OUT_DIM + 256 + lane * 4);
            s0.x += p0.x; s0.y += p0.y; s0.z += p0.z; s0.w += p0.w;
            s1.x += p1.x; s1.y += p1.y; s1.z += p1.z; s1.w += p1.w;
        }
        es[lane * 4 + 0] = tanhf(s0.x);
        es[lane * 4 + 1] = tanhf(s0.y);
        es[lane * 4 + 2] = tanhf(s0.z);
        es[lane * 4 + 3] = tanhf(s0.w);
        es[256 + lane * 4 + 0] = tanhf(s1.x);
        es[256 + lane * 4 + 1] = tanhf(s1.y);
        es[256 + lane * 4 + 2] = tanhf(s1.z);
        es[256 + lane * 4 + 3] = tanhf(s1.w);
    }
    __syncthreads();

    const float4 e0 = *(const float4*)(es + lane * 4);
    const float4 e1 = *(const float4*)(es + 256 + lane * 4);

    const int base = blockIdx.x * ROWS_PER_BLOCK + w * 16;
    const float* mrow = memory + (size_t)base * OUT_DIM;
#pragma unroll 4
    for (int r = 0; r < 16; ++r) {
        const float4 m0 = *(const float4*)(mrow + lane * 4);
        const float4 m1 = *(const float4*)(mrow + 256 + lane * 4);
        float s = fabsf(m0.x - e0.x) + fabsf(m0.y - e0.y)
                + fabsf(m0.z - e0.z) + fabsf(m0.w - e0.w)
                + fabsf(m1.x - e1.x) + fabsf(m1.y - e1.y)
                + fabsf(m1.z - e1.z) + fabsf(m1.w - e1.w);
#pragma unroll
        for (int off = 32; off > 0; off >>= 1)
            s += __shfl_down(s, off, 64);
        if (lane == 0) bd[w * 16 + r] = s;
        mrow += OUT_DIM;
    }
    __syncthreads();

    // Wave 0: 16 smallest of the 64 block dists, in-register (1 value/lane).
    if (t < 64) {
        float v = bd[t];
#pragma unroll 1
        for (int k = 0; k < K_TOP; ++k) {
            float m = v;
#pragma unroll
            for (int off = 32; off > 0; off >>= 1)
                m = fminf(m, __shfl_xor(m, off, 64));
            unsigned long long mask = __ballot(v == m);
            int src = __ffsll(mask) - 1;
            if (t == src) v = FLT_MAX;
            if (t == 0) cand[blockIdx.x * K_TOP + k] = m;
        }
    }
}

// ---------------------------------------------------------------------------
// Kernel 3: exact global top-16 over 32768 candidates (L2-resident), loss.
__global__ void final_topk_kernel(const float* __restrict__ cand,
                                  const float* __restrict__ exp_w,
                                  float* __restrict__ out) {
    __shared__ float cands[256][K_TOP + 1];
    __shared__ float redv[256];
    __shared__ int flag;
    const int t = threadIdx.x;

    for (int j = 0; j < K_TOP; ++j) cands[t][j] = FLT_MAX;
    float cmax = FLT_MAX;
    int cmaxi = 0;

    for (int i = t; i < CAND_N; i += 256) {
        float d = cand[i];
        if (d < cmax) {
            cands[t][cmaxi] = d;
            cmax = cands[t][0]; cmaxi = 0;
            for (int j = 1; j < K_TOP; ++j)
                if (cands[t][j] > cmax) { cmax = cands[t][j]; cmaxi = j; }
        }
    }
    __syncthreads();

    float num = 0.0f;
    for (int k = 0; k < K_TOP; ++k) {
        float lmin = cands[t][0];
        for (int j = 1; j < K_TOP; ++j) lmin = fminf(lmin, cands[t][j]);
        redv[t] = lmin;
        if (t == 0) flag = 0;
        __syncthreads();
        for (int s = 128; s > 0; s >>= 1) {
            if (t < s) redv[t] = fminf(redv[t], redv[t + s]);
            __syncthreads();
        }
        float gmin = redv[0];
        int ji = -1;
        for (int j = 0; j < K_TOP; ++j)
            if (cands[t][j] == gmin) { ji = j; break; }
        if (ji >= 0 && atomicExch(&flag, 1) == 0) cands[t][ji] = FLT_MAX;
        __syncthreads();
        if (t == 0) num += gmin * exp_w[k];
    }

    if (t == 0) {
        float den = 0.0f;
        for (int k = 0; k < K_TOP; ++k) den += exp_w[k];
        out[0] = num / den;
    }
}

extern "C" void kernel_launch(void* const* d_in, const int* in_sizes, int n_in,
                              void* d_out, int out_size, void* d_ws, size_t ws_size,
                              hipStream_t stream) {
    const float* data   = (const float*)d_in[0];
    const float* mean   = (const float*)d_in[1];
    const float* stdv   = (const float*)d_in[2];
    const float* memory = (const float*)d_in[3];
    const float* W      = (const float*)d_in[4];
    const float* b      = (const float*)d_in[5];
    const float* exp_w  = (const float*)d_in[6];
    float* out = (float*)d_out;

    float* partial = (float*)d_ws;                       // 32*512 floats (64 KB)
    float* cand    = partial + GEMV_BLOCKS * OUT_DIM;    // 32768 floats (128 KB)

    gemv_partial_kernel<<<GEMV_BLOCKS, OUT_DIM, 0, stream>>>(data, mean, stdv, W, b, partial);
    dist_topk_kernel<<<DIST_BLOCKS, 256, 0, stream>>>(partial, memory, cand);
    final_topk_kernel<<<1, 256, 0, stream>>>(cand, exp_w, out);
}

// Round 5
// 380.557 us; speedup vs baseline: 1.2208x; 1.2208x over previous
//
#include <hip/hip_runtime.h>
#include <math.h>
#include <float.h>

#define IN_DIM 256
#define OUT_DIM 512
#define MEM_LEN 131072
#define K_TOP 16

#define GEMV_BLOCKS 32
#define K_PER_BLOCK (IN_DIM / GEMV_BLOCKS)      // 8
#define DIST_BLOCKS 2048
#define SEL_BLOCKS 32
#define SEL_SPAN (MEM_LEN / SEL_BLOCKS)         // 4096 dists per selection block
#define CAND_N (SEL_BLOCKS * K_TOP)             // 512

__device__ __forceinline__ void ce(float& a, float& b) {
    float lo = fminf(a, b);
    float hi = fmaxf(a, b);
    a = lo; b = hi;
}

// Sort 16 registers ascending: odd-even transposition network (branchless).
__device__ __forceinline__ void sort16(float v[16]) {
#pragma unroll
    for (int p = 0; p < 16; ++p) {
#pragma unroll
        for (int i = 0; i < 15; ++i)
            if ((i & 1) == (p & 1)) ce(v[i], v[i + 1]);
    }
}

// Merge my sorted-16 with xor-partner lane's sorted-16, keep smallest 16 sorted.
// m[i] = min(A[i], B[15-i]) is the smallest-16 as a bitonic seq (bitonic split);
// then 4-stage bitonic merge network sorts it ascending. Exact.
__device__ __forceinline__ void merge_lanes(float v[16], int offset) {
    float w[16];
#pragma unroll
    for (int i = 0; i < 16; ++i) w[i] = __shfl_xor(v[i], offset, 64);
    float m[16];
#pragma unroll
    for (int i = 0; i < 16; ++i) m[i] = fminf(v[i], w[15 - i]);
#pragma unroll
    for (int d = 8; d >= 1; d >>= 1) {
#pragma unroll
        for (int i = 0; i < 16; ++i)
            if ((i & d) == 0) ce(m[i], m[i | d]);
    }
#pragma unroll
    for (int i = 0; i < 16; ++i) v[i] = m[i];
}

// ---------------------------------------------------------------------------
// Kernel 1: split-K GEMV partials (atomic-free; bias folded into slice 0).
__global__ void gemv_partial_kernel(const float* __restrict__ data,
                                    const float* __restrict__ mean,
                                    const float* __restrict__ stdv,
                                    const float* __restrict__ W,
                                    const float* __restrict__ b,
                                    float* __restrict__ partial) {
    __shared__ float xn_s[K_PER_BLOCK];
    const int t = threadIdx.x;        // column 0..511
    const int g = blockIdx.x;         // K-slice
    if (t < K_PER_BLOCK) {
        int i = g * K_PER_BLOCK + t;
        float s = stdv[i];
        xn_s[t] = (s == 0.0f) ? 0.0f : (data[i] - mean[i]) / s;
    }
    __syncthreads();
    float acc = (g == 0) ? b[t] : 0.0f;
#pragma unroll
    for (int j = 0; j < K_PER_BLOCK; ++j)
        acc = fmaf(xn_s[j], W[(g * K_PER_BLOCK + j) * OUT_DIM + t], acc);
    partial[g * OUT_DIM + t] = acc;
}

// ---------------------------------------------------------------------------
// Kernel 2: enc[t] = tanh(sum_g partial[g][t]). One block, 512 threads.
__global__ void enc_reduce_kernel(const float* __restrict__ partial,
                                  float* __restrict__ enc) {
    const int t = threadIdx.x;
    float s = 0.0f;
#pragma unroll 8
    for (int g = 0; g < GEMV_BLOCKS; ++g) s += partial[g * OUT_DIM + t];
    enc[t] = tanhf(s);
}

// ---------------------------------------------------------------------------
// Kernel 3: pure streaming dist (proven R3 shape). One wave per 16 consecutive
// rows; 2x float4 per lane covers the full 2KB row. No LDS, no barriers.
__global__ __launch_bounds__(256)
void dist_kernel(const float* __restrict__ memory,
                 const float* __restrict__ enc,
                 float* __restrict__ dist) {
    const int lane = threadIdx.x & 63;
    const int wave = blockIdx.x * 4 + (threadIdx.x >> 6);

    const float4 e0 = *(const float4*)(enc + lane * 4);
    const float4 e1 = *(const float4*)(enc + 256 + lane * 4);

    const int row0 = wave * 16;
    const float* mrow = memory + (size_t)row0 * OUT_DIM;
#pragma unroll 2
    for (int r = 0; r < 16; ++r) {
        const float4 m0 = *(const float4*)(mrow + lane * 4);
        const float4 m1 = *(const float4*)(mrow + 256 + lane * 4);
        float s = fabsf(m0.x - e0.x) + fabsf(m0.y - e0.y)
                + fabsf(m0.z - e0.z) + fabsf(m0.w - e0.w)
                + fabsf(m1.x - e1.x) + fabsf(m1.y - e1.y)
                + fabsf(m1.z - e1.z) + fabsf(m1.w - e1.w);
#pragma unroll
        for (int off = 32; off > 0; off >>= 1)
            s += __shfl_down(s, off, 64);
        if (lane == 0) dist[row0 + r] = s;
        mrow += OUT_DIM;
    }
}

// ---------------------------------------------------------------------------
// Kernel 4: bitonic top-16 selection. 32 blocks x 256 threads. Each wave owns
// 1024 dists (16/lane, coalesced i*64+lane), sorts 16 in registers, 6 shuffle
// merge rounds -> wave top-16 sorted; 4 wave lists merged via LDS by wave 0.
__global__ __launch_bounds__(256)
void select_kernel(const float* __restrict__ dist,
                   float* __restrict__ cand) {
    __shared__ float ws16[4][16];
    const int t = threadIdx.x;
    const int lane = t & 63;
    const int w = t >> 6;
    const int base = blockIdx.x * SEL_SPAN + w * 1024;

    float v[16];
#pragma unroll
    for (int i = 0; i < 16; ++i) v[i] = dist[base + i * 64 + lane];
    sort16(v);
    merge_lanes(v, 1);
    merge_lanes(v, 2);
    merge_lanes(v, 4);
    merge_lanes(v, 8);
    merge_lanes(v, 16);
    merge_lanes(v, 32);
    if (lane == 0) {
#pragma unroll
        for (int i = 0; i < 16; ++i) ws16[w][i] = v[i];
    }
    __syncthreads();

    if (t < 64) {
        float u[16];
#pragma unroll
        for (int i = 0; i < 16; ++i) u[i] = (lane < 4) ? ws16[lane & 3][i] : FLT_MAX;
        merge_lanes(u, 1);
        merge_lanes(u, 2);
        if (lane == 0) {
#pragma unroll
            for (int i = 0; i < 16; ++i) cand[blockIdx.x * K_TOP + i] = u[i];
        }
    }
}

// ---------------------------------------------------------------------------
// Kernel 5: final merge of 32 sorted 16-lists (512 floats) + weighted loss.
// One wave: lane l<32 holds list l; 5 merge rounds -> lane 0 has global
// sorted top-16 ascending.
__global__ void final_kernel(const float* __restrict__ cand,
                             const float* __restrict__ exp_w,
                             float* __restrict__ out) {
    const int lane = threadIdx.x & 63;
    float v[16];
#pragma unroll
    for (int i = 0; i < 16; ++i)
        v[i] = (lane < SEL_BLOCKS) ? cand[lane * K_TOP + i] : FLT_MAX;
    merge_lanes(v, 1);
    merge_lanes(v, 2);
    merge_lanes(v, 4);
    merge_lanes(v, 8);
    merge_lanes(v, 16);
    if (lane == 0) {
        float num = 0.0f, den = 0.0f;
#pragma unroll
        for (int k = 0; k < K_TOP; ++k) {
            float wk = exp_w[k];
            num = fmaf(v[k], wk, num);
            den += wk;
        }
        out[0] = num / den;
    }
}

extern "C" void kernel_launch(void* const* d_in, const int* in_sizes, int n_in,
                              void* d_out, int out_size, void* d_ws, size_t ws_size,
                              hipStream_t stream) {
    const float* data   = (const float*)d_in[0];
    const float* mean   = (const float*)d_in[1];
    const float* stdv   = (const float*)d_in[2];
    const float* memory = (const float*)d_in[3];
    const float* W      = (const float*)d_in[4];
    const float* b      = (const float*)d_in[5];
    const float* exp_w  = (const float*)d_in[6];
    float* out = (float*)d_out;

    float* partial = (float*)d_ws;                       // 32*512 floats
    float* enc     = partial + GEMV_BLOCKS * OUT_DIM;    // 512 floats
    float* dist    = enc + OUT_DIM;                      // 131072 floats
    float* cand    = dist + MEM_LEN;                     // 512 floats

    gemv_partial_kernel<<<GEMV_BLOCKS, OUT_DIM, 0, stream>>>(data, mean, stdv, W, b, partial);
    enc_reduce_kernel<<<1, OUT_DIM, 0, stream>>>(partial, enc);
    dist_kernel<<<DIST_BLOCKS, 256, 0, stream>>>(memory, enc, dist);
    select_kernel<<<SEL_BLOCKS, 256, 0, stream>>>(dist, cand);
    final_kernel<<<1, 64, 0, stream>>>(cand, exp_w, out);
}

// Round 6
// 378.857 us; speedup vs baseline: 1.2263x; 1.0045x over previous
//
#include <hip/hip_runtime.h>
#include <math.h>
#include <float.h>

#define IN_DIM 256
#define OUT_DIM 512
#define MEM_LEN 131072
#define K_TOP 16

#define GEMV_BLOCKS 32
#define K_PER_BLOCK (IN_DIM / GEMV_BLOCKS)      // 8
#define DIST_BLOCKS 2048
#define ROWS_PER_BLOCK (MEM_LEN / DIST_BLOCKS)  // 64
#define CAND1_N (DIST_BLOCKS * K_TOP)           // 32768
#define SEL2_BLOCKS 8
#define SEL2_SPAN (CAND1_N / SEL2_BLOCKS)       // 4096
#define CAND2_N (SEL2_BLOCKS * K_TOP)           // 128

__device__ __forceinline__ void ce(float& a, float& b) {
    float lo = fminf(a, b);
    float hi = fmaxf(a, b);
    a = lo; b = hi;
}

// Sort 16 registers ascending: odd-even transposition network (branchless).
__device__ __forceinline__ void sort16(float v[16]) {
#pragma unroll
    for (int p = 0; p < 16; ++p) {
#pragma unroll
        for (int i = 0; i < 15; ++i)
            if ((i & 1) == (p & 1)) ce(v[i], v[i + 1]);
    }
}

// Merge my sorted-16 with xor-partner lane's sorted-16, keep smallest 16
// sorted ascending (bitonic split + 4-stage merge). Both partners end with
// the identical merged list (min is symmetric). Exact.
__device__ __forceinline__ void merge_lanes(float v[16], int offset) {
    float w[16];
#pragma unroll
    for (int i = 0; i < 16; ++i) w[i] = __shfl_xor(v[i], offset, 64);
    float m[16];
#pragma unroll
    for (int i = 0; i < 16; ++i) m[i] = fminf(v[i], w[15 - i]);
#pragma unroll
    for (int d = 8; d >= 1; d >>= 1) {
#pragma unroll
        for (int i = 0; i < 16; ++i)
            if ((i & d) == 0) ce(m[i], m[i | d]);
    }
#pragma unroll
    for (int i = 0; i < 16; ++i) v[i] = m[i];
}

// ---------------------------------------------------------------------------
// Kernel 1: split-K GEMV partials (atomic-free; bias folded into slice 0).
__global__ void gemv_partial_kernel(const float* __restrict__ data,
                                    const float* __restrict__ mean,
                                    const float* __restrict__ stdv,
                                    const float* __restrict__ W,
                                    const float* __restrict__ b,
                                    float* __restrict__ partial) {
    __shared__ float xn_s[K_PER_BLOCK];
    const int t = threadIdx.x;        // column 0..511
    const int g = blockIdx.x;         // K-slice
    if (t < K_PER_BLOCK) {
        int i = g * K_PER_BLOCK + t;
        float s = stdv[i];
        xn_s[t] = (s == 0.0f) ? 0.0f : (data[i] - mean[i]) / s;
    }
    __syncthreads();
    float acc = (g == 0) ? b[t] : 0.0f;
#pragma unroll
    for (int j = 0; j < K_PER_BLOCK; ++j)
        acc = fmaf(xn_s[j], W[(g * K_PER_BLOCK + j) * OUT_DIM + t], acc);
    partial[g * OUT_DIM + t] = acc;
}

// ---------------------------------------------------------------------------
// Kernel 2: fused enc-reduce + dist stream + per-block bitonic top-16.
// 2048 blocks x 256 threads (4 waves x 16 rows = 64 rows/block).
// enc reduction parallel across all 256 threads (2 cols each, 32 partials).
// Tail: wave 0 bitonic-sorts the 64 block dists across lanes (21 branchless
// CE-shuffle steps); lanes 0..15 write the sorted top-16 to cand1.
__global__ __launch_bounds__(256)
void dist_topk_kernel(const float* __restrict__ partial,
                      const float* __restrict__ memory,
                      float* __restrict__ cand1) {
    __shared__ float es[OUT_DIM];
    __shared__ float bd[ROWS_PER_BLOCK];
    const int t = threadIdx.x;
    const int lane = t & 63;
    const int w = t >> 6;

    // enc[t], enc[t+256] = tanh(sum_g partial[g][.]) — coalesced, all threads.
    {
        float s0 = 0.0f, s1 = 0.0f;
#pragma unroll 8
        for (int g = 0; g < GEMV_BLOCKS; ++g) {
            s0 += partial[g * OUT_DIM + t];
            s1 += partial[g * OUT_DIM + 256 + t];
        }
        es[t] = tanhf(s0);
        es[256 + t] = tanhf(s1);
    }
    __syncthreads();

    const float4 e0 = *(const float4*)(es + lane * 4);
    const float4 e1 = *(const float4*)(es + 256 + lane * 4);

    const int base = blockIdx.x * ROWS_PER_BLOCK + w * 16;
    const float* mrow = memory + (size_t)base * OUT_DIM;
#pragma unroll 2
    for (int r = 0; r < 16; ++r) {
        const float4 m0 = *(const float4*)(mrow + lane * 4);
        const float4 m1 = *(const float4*)(mrow + 256 + lane * 4);
        float s = fabsf(m0.x - e0.x) + fabsf(m0.y - e0.y)
                + fabsf(m0.z - e0.z) + fabsf(m0.w - e0.w)
                + fabsf(m1.x - e1.x) + fabsf(m1.y - e1.y)
                + fabsf(m1.z - e1.z) + fabsf(m1.w - e1.w);
#pragma unroll
        for (int off = 32; off > 0; off >>= 1)
            s += __shfl_down(s, off, 64);
        if (lane == 0) bd[w * 16 + r] = s;
        mrow += OUT_DIM;
    }
    __syncthreads();

    // Wave 0: full bitonic sort of 64 values across lanes, ascending.
    if (t < 64) {
        float v = bd[t];
#pragma unroll
        for (int k = 2; k <= 64; k <<= 1) {
#pragma unroll
            for (int j = k >> 1; j > 0; j >>= 1) {
                float pv = __shfl_xor(v, j, 64);
                bool up = ((t & k) == 0);
                bool takeMin = (((t & j) == 0) == up);
                v = takeMin ? fminf(v, pv) : fmaxf(v, pv);
            }
        }
        if (t < K_TOP) cand1[blockIdx.x * K_TOP + t] = v;
    }
}

// ---------------------------------------------------------------------------
// Kernel 3: bitonic top-16 over 32768 candidates. 8 blocks x 256 threads.
// Each wave: 1024 cands (16/lane coalesced), sort16 + 6 merge rounds; the 4
// wave lists merged via LDS by wave 0 -> cand2[block*16..+16] sorted.
__global__ __launch_bounds__(256)
void select2_kernel(const float* __restrict__ cand1,
                    float* __restrict__ cand2) {
    __shared__ float ws16[4][16];
    const int t = threadIdx.x;
    const int lane = t & 63;
    const int w = t >> 6;
    const int base = blockIdx.x * SEL2_SPAN + w * 1024;

    float v[16];
#pragma unroll
    for (int i = 0; i < 16; ++i) v[i] = cand1[base + i * 64 + lane];
    sort16(v);
    merge_lanes(v, 1);
    merge_lanes(v, 2);
    merge_lanes(v, 4);
    merge_lanes(v, 8);
    merge_lanes(v, 16);
    merge_lanes(v, 32);
    if (lane == 0) {
#pragma unroll
        for (int i = 0; i < 16; ++i) ws16[w][i] = v[i];
    }
    __syncthreads();

    if (t < 64) {
        float u[16];
#pragma unroll
        for (int i = 0; i < 16; ++i) u[i] = (lane < 4) ? ws16[lane & 3][i] : FLT_MAX;
        merge_lanes(u, 1);
        merge_lanes(u, 2);
        if (lane == 0) {
#pragma unroll
            for (int i = 0; i < 16; ++i) cand2[blockIdx.x * K_TOP + i] = u[i];
        }
    }
}

// ---------------------------------------------------------------------------
// Kernel 4: final merge of 8 sorted 16-lists (128 floats) + weighted loss.
__global__ void final_kernel(const float* __restrict__ cand2,
                             const float* __restrict__ exp_w,
                             float* __restrict__ out) {
    const int lane = threadIdx.x & 63;
    float v[16];
#pragma unroll
    for (int i = 0; i < 16; ++i)
        v[i] = (lane < SEL2_BLOCKS) ? cand2[lane * K_TOP + i] : FLT_MAX;
    merge_lanes(v, 1);
    merge_lanes(v, 2);
    merge_lanes(v, 4);
    if (lane == 0) {
        float num = 0.0f, den = 0.0f;
#pragma unroll
        for (int k = 0; k < K_TOP; ++k) {
            float wk = exp_w[k];
            num = fmaf(v[k], wk, num);
            den += wk;
        }
        out[0] = num / den;
    }
}

extern "C" void kernel_launch(void* const* d_in, const int* in_sizes, int n_in,
                              void* d_out, int out_size, void* d_ws, size_t ws_size,
                              hipStream_t stream) {
    const float* data   = (const float*)d_in[0];
    const float* mean   = (const float*)d_in[1];
    const float* stdv   = (const float*)d_in[2];
    const float* memory = (const float*)d_in[3];
    const float* W      = (const float*)d_in[4];
    const float* b      = (const float*)d_in[5];
    const float* exp_w  = (const float*)d_in[6];
    float* out = (float*)d_out;

    float* partial = (float*)d_ws;                       // 32*512 floats
    float* cand1   = partial + GEMV_BLOCKS * OUT_DIM;    // 32768 floats
    float* cand2   = cand1 + CAND1_N;                    // 128 floats

    gemv_partial_kernel<<<GEMV_BLOCKS, OUT_DIM, 0, stream>>>(data, mean, stdv, W, b, partial);
    dist_topk_kernel<<<DIST_BLOCKS, 256, 0, stream>>>(partial, memory, cand1);
    select2_kernel<<<SEL2_BLOCKS, 256, 0, stream>>>(cand1, cand2);
    final_kernel<<<1, 64, 0, stream>>>(cand2, exp_w, out);
}